// Round 5
// baseline (686.093 us; speedup 1.0000x reference)
//
#include <hip/hip_runtime.h>
#include <hip/hip_bf16.h>

typedef __hip_bfloat16 bf16;
typedef __attribute__((ext_vector_type(8))) short short8v;  // 8 bf16 = 4 VGPR
typedef __attribute__((ext_vector_type(4))) float f32x4;    // MFMA C/D frag

#define B_   2
#define T_   2048
#define D_   512
#define H_   8
#define DK_  64
#define DFF_ 2048
#define M_   (B_*T_)   // 4096 rows

static __device__ __forceinline__ float b2f(bf16 v) { return __bfloat162float(v); }
static __device__ __forceinline__ bf16  f2b(float v){ return __float2bfloat16(v); }

// Flagged load/store: bf==true -> buffer is bf16, else fp32.
static __device__ __forceinline__ float ldin(const void* p, size_t i, bool bf) {
    return bf ? __bfloat162float(((const bf16*)p)[i]) : ((const float*)p)[i];
}
static __device__ __forceinline__ void stout(void* p, size_t i, float v, bool bf) {
    if (bf) ((bf16*)p)[i] = __float2bfloat16(v);
    else    ((float*)p)[i] = v;
}
// hi/lo bf16 split of an fp32 value (bit patterns as shorts)
static __device__ __forceinline__ short hi_of(float v) {
    bf16 h = f2b(v);
    return *(const short*)&h;
}
static __device__ __forceinline__ short lo_of(float v) {
    bf16 h = f2b(v);
    bf16 l = f2b(v - b2f(h));
    return *(const short*)&l;
}

// ---------------------------------------------------------------------------
// Dtype detector (parallel): bf16 low-16-bits look like in-range bf16 values.
// flag=1 -> bf16, flag=0 -> fp32.
// ---------------------------------------------------------------------------
__global__ void detect_dtype(const unsigned int* __restrict__ x, int* __restrict__ flag)
{
    __shared__ int cnt;
    if (threadIdx.x == 0) cnt = 0;
    __syncthreads();
    int local = 0;
    for (int i = threadIdx.x; i < 1024; i += 256) {
        unsigned int lo = x[i] & 0xFFFFu;
        float v = __uint_as_float(lo << 16);
        float a = fabsf(v);
        if (a > 1e-3f && a < 16.f) local++;
    }
    atomicAdd(&cnt, local);
    __syncthreads();
    if (threadIdx.x == 0) *flag = (cnt > 512) ? 1 : 0;
}

// ---------------------------------------------------------------------------
// split_x: x [M_*D_] (dtype per flag) -> xh, xl bf16 planes (xl skipped when
// native bf16: then xh is an exact copy and xl is never read downstream).
// ---------------------------------------------------------------------------
__global__ __launch_bounds__(256)
void split_x(const void* __restrict__ X, bf16* __restrict__ xh,
             bf16* __restrict__ xl, const int* __restrict__ flag)
{
    const bool bf = (*flag != 0);
    const size_t i = ((size_t)blockIdx.x * 256 + threadIdx.x) * 8;
    if (bf) {
        *(short8v*)(xh + i) = *(const short8v*)((const bf16*)X + i);
    } else {
        const float* Xf = (const float*)X + i;
        const float4 f0 = *(const float4*)(Xf);
        const float4 f1 = *(const float4*)(Xf + 4);
        const float vals[8] = {f0.x, f0.y, f0.z, f0.w, f1.x, f1.y, f1.z, f1.w};
        short8v hi, lo;
        #pragma unroll
        for (int j = 0; j < 8; ++j) {
            short th = hi_of(vals[j]);
            short tl = lo_of(vals[j]);
            hi[j] = th;
            lo[j] = tl;
        }
        *(short8v*)(xh + i) = hi;
        *(short8v*)(xl + i) = lo;
    }
}

// ---------------------------------------------------------------------------
// Weight transpose + bf16 split (with optional scale, exact for pow2):
// W[K][N] -> Wt_hi[N][K], Wt_lo[N][K].
// ---------------------------------------------------------------------------
__global__ __launch_bounds__(256)
void transpose_w(const void* __restrict__ W, bf16* __restrict__ oh,
                 bf16* __restrict__ ol, const int* __restrict__ flag,
                 int K, int N, float scale)
{
    const bool bf = (*flag != 0);
    __shared__ float tile[32][33];
    const int n0 = blockIdx.x * 32;
    const int k0 = blockIdx.y * 32;
    const int c  = threadIdx.x & 31;
    const int r8 = threadIdx.x >> 5;

    #pragma unroll
    for (int i = 0; i < 4; ++i) {
        int r = r8 + i * 8;
        tile[r][c] = ldin(W, (size_t)(k0 + r) * N + n0 + c, bf) * scale;
    }
    __syncthreads();
    #pragma unroll
    for (int i = 0; i < 4; ++i) {
        int r = r8 + i * 8;                  // n within tile
        float v = tile[c][r];                // = scale * W[k0+c][n0+r]
        bf16 h = f2b(v);
        oh[(size_t)(n0 + r) * K + k0 + c] = h;
        if (!bf) ol[(size_t)(n0 + r) * K + k0 + c] = f2b(v - b2f(h));
    }
}

// ---------------------------------------------------------------------------
// MFMA GEMM, pre-split operands. C[M,N] = A @ B + bias*bscale.
// A: bf16 hi/lo planes [M][K]; B: bf16 hi/lo planes [N][K] (pre-transposed).
// Products: Ah*Bh always; + Al*Bh if A inexact; + Ah*Bl if weights fp32.
//   NA=1: A is exact bf16 in bf16 mode (x). NA=0: A is a split intermediate.
// OBF: 0 fp32 out, 1 bf16 out, 2 bf16 hi/lo plane out, 3 bf16 TRANSPOSED out.
// Tile BM=128 x BN (64/128), BK=32, 4 waves as 2x2, per-wave 64 x BN/2
// (4 x BN/32 frags of 16x16x32). Frag & C/D layouts harness-verified.
// LDS: (2*128 + 2*BN) x 40 shorts = 30/40 KB.
// ---------------------------------------------------------------------------
template<int BN, int NA, int RELU, int OBF>
__global__ __launch_bounds__(256)
void gemm_mfma(const bf16* __restrict__ Ahg, const bf16* __restrict__ Alg,
               const bf16* __restrict__ BTh, const bf16* __restrict__ BTl,
               const void* __restrict__ bias, const int* __restrict__ flag,
               void* __restrict__ C, bf16* __restrict__ Cl,
               int M, int N, int K, float bscale)
{
    constexpr int BM = 128;
    constexpr int FM = 4;
    constexpr int FN = BN / 32;
    const bool bfw   = (*flag != 0);
    const bool useAl = !(NA == 1 && bfw);
    const bool useBl = !bfw;

    __shared__ short As[2][BM][40];
    __shared__ short Bs[2][BN][40];

    const int tid  = threadIdx.x;
    const int lane = tid & 63;
    const int wave = tid >> 6;
    const int wm   = wave >> 1;
    const int wn   = wave & 1;
    const int rowBase = blockIdx.y * BM;
    const int colBase = blockIdx.x * BN;

    const int fr = lane & 15;
    const int kb = (lane >> 4) * 8;

    // staging coords
    const int arow = tid >> 1;                 // 0..127
    const int acol = (tid & 1) * 16;
    const int brow = (BN == 128) ? (tid >> 1) : (tid >> 2);
    const int bcol = (BN == 128) ? ((tid & 1) * 16) : ((tid & 3) * 8);

    const bf16* aHs = Ahg + (size_t)(rowBase + arow) * K + acol;
    const bf16* aLs = Alg + (size_t)(rowBase + arow) * K + acol;
    const bf16* bHs = BTh + (size_t)(colBase + brow) * K + bcol;
    const bf16* bLs = BTl + (size_t)(colBase + brow) * K + bcol;

    f32x4 acc[FM][FN] = {};

    for (int k0 = 0; k0 < K; k0 += 32) {
        __syncthreads();
        *(short8v*)&As[0][arow][acol]     = *(const short8v*)(aHs + k0);
        *(short8v*)&As[0][arow][acol + 8] = *(const short8v*)(aHs + k0 + 8);
        if (useAl) {
            *(short8v*)&As[1][arow][acol]     = *(const short8v*)(aLs + k0);
            *(short8v*)&As[1][arow][acol + 8] = *(const short8v*)(aLs + k0 + 8);
        }
        if (BN == 128) {
            *(short8v*)&Bs[0][brow][bcol]     = *(const short8v*)(bHs + k0);
            *(short8v*)&Bs[0][brow][bcol + 8] = *(const short8v*)(bHs + k0 + 8);
            if (useBl) {
                *(short8v*)&Bs[1][brow][bcol]     = *(const short8v*)(bLs + k0);
                *(short8v*)&Bs[1][brow][bcol + 8] = *(const short8v*)(bLs + k0 + 8);
            }
        } else {
            *(short8v*)&Bs[0][brow][bcol] = *(const short8v*)(bHs + k0);
            if (useBl)
                *(short8v*)&Bs[1][brow][bcol] = *(const short8v*)(bLs + k0);
        }
        __syncthreads();

        short8v aH[FM], aL[FM], bH[FN], bL[FN];
        #pragma unroll
        for (int f = 0; f < FM; ++f)
            aH[f] = *(const short8v*)&As[0][wm * 64 + f * 16 + fr][kb];
        if (useAl) {
            #pragma unroll
            for (int f = 0; f < FM; ++f)
                aL[f] = *(const short8v*)&As[1][wm * 64 + f * 16 + fr][kb];
        }
        #pragma unroll
        for (int f = 0; f < FN; ++f)
            bH[f] = *(const short8v*)&Bs[0][wn * (BN/2) + f * 16 + fr][kb];
        if (useBl) {
            #pragma unroll
            for (int f = 0; f < FN; ++f)
                bL[f] = *(const short8v*)&Bs[1][wn * (BN/2) + f * 16 + fr][kb];
        }

        #pragma unroll
        for (int i = 0; i < FM; ++i)
            #pragma unroll
            for (int j = 0; j < FN; ++j) {
                acc[i][j] = __builtin_amdgcn_mfma_f32_16x16x32_bf16(aH[i], bH[j], acc[i][j], 0, 0, 0);
                if (useAl)
                    acc[i][j] = __builtin_amdgcn_mfma_f32_16x16x32_bf16(aL[i], bH[j], acc[i][j], 0, 0, 0);
                if (useBl)
                    acc[i][j] = __builtin_amdgcn_mfma_f32_16x16x32_bf16(aH[i], bL[j], acc[i][j], 0, 0, 0);
            }
    }

    // epilogue: C/D layout col=lane&15, row=(lane>>4)*4+q (verified)
    const int rq = (lane >> 4) * 4;
    #pragma unroll
    for (int j = 0; j < FN; ++j) {
        const int col = colBase + wn * (BN/2) + j * 16 + fr;
        const float bv = ldin(bias, col, bfw) * bscale;
        #pragma unroll
        for (int i = 0; i < FM; ++i) {
            #pragma unroll
            for (int q = 0; q < 4; ++q) {
                float v = acc[i][j][q] + bv;
                if (RELU) v = fmaxf(v, 0.f);
                const int row = rowBase + wm * 64 + i * 16 + rq + q;
                if (OBF == 0) {
                    ((float*)C)[(size_t)row * N + col] = v;
                } else if (OBF == 1) {
                    ((bf16*)C)[(size_t)row * N + col] = f2b(v);
                } else if (OBF == 2) {
                    size_t idx = (size_t)row * N + col;
                    bf16 h = f2b(v);
                    ((bf16*)C)[idx] = h;
                    Cl[idx] = f2b(v - b2f(h));
                } else {  // OBF == 3: transposed bf16 out [N][M]
                    ((bf16*)C)[(size_t)col * M + row] = f2b(v);
                }
            }
        }
    }
}

// ---------------------------------------------------------------------------
// Two-pass MFMA attention (core unchanged; epilogue emits ctx hi/lo planes).
// ---------------------------------------------------------------------------
__global__ __launch_bounds__(256)
void attn_mfma(const bf16* __restrict__ Qb, const bf16* __restrict__ Kb,
               const bf16* __restrict__ VTb, void* __restrict__ dout,
               const int* __restrict__ flag,
               bf16* __restrict__ ctxh, bf16* __restrict__ ctxl)
{
    const bool bf = (*flag != 0);
    const int tid  = threadIdx.x;
    const int lane = tid & 63;
    const int wave = tid >> 6;
    const int wm = wave >> 1, wn = wave & 1;
    const int q0 = blockIdx.x * 64;
    const int h  = blockIdx.y;
    const int b  = blockIdx.z;
    const size_t OFFOUT = (size_t)M_ * D_;

    __shared__ short Qs[64][72];
    __shared__ short Ks[64][72];
    __shared__ short Vs[64][72];
    __shared__ short Ps[64][72];
    __shared__ float Lp[2][64];
    __shared__ float invl_s[64];

    const int fr = lane & 15;
    const int kb = (lane >> 4) * 8;

    // stage Q (bf16, pre-scaled)
    #pragma unroll
    for (int l = 0; l < 2; ++l) {
        int idx = tid + l * 256;
        int r = idx >> 3, c8 = (idx & 7) * 8;
        *(short8v*)&Qs[r][c8] =
            *(const short8v*)(Qb + (size_t)(b*T_ + q0 + r) * D_ + h*DK_ + c8);
    }

    // ---------------- pass A: denominators ----------------
    float lsum[2][4] = {};

    for (int kt = 0; kt < T_/64; ++kt) {
        __syncthreads();
        #pragma unroll
        for (int l = 0; l < 2; ++l) {
            int idx = tid + l * 256;
            int r = idx >> 3, c8 = (idx & 7) * 8;
            *(short8v*)&Ks[r][c8] =
                *(const short8v*)(Kb + (size_t)(b*T_ + kt*64 + r) * D_ + h*DK_ + c8);
        }
        __syncthreads();

        short8v aF[2][2], bF[2][2];
        #pragma unroll
        for (int i = 0; i < 2; ++i)
            #pragma unroll
            for (int k2 = 0; k2 < 2; ++k2)
                aF[i][k2] = *(const short8v*)&Qs[wm*32 + i*16 + fr][kb + k2*32];
        #pragma unroll
        for (int j = 0; j < 2; ++j)
            #pragma unroll
            for (int k2 = 0; k2 < 2; ++k2)
                bF[j][k2] = *(const short8v*)&Ks[wn*32 + j*16 + fr][kb + k2*32];

        #pragma unroll
        for (int i = 0; i < 2; ++i)
            #pragma unroll
            for (int j = 0; j < 2; ++j) {
                f32x4 s = {};
                s = __builtin_amdgcn_mfma_f32_16x16x32_bf16(aF[i][0], bF[j][0], s, 0, 0, 0);
                s = __builtin_amdgcn_mfma_f32_16x16x32_bf16(aF[i][1], bF[j][1], s, 0, 0, 0);
                #pragma unroll
                for (int q = 0; q < 4; ++q)
                    lsum[i][q] += __expf(fminf(s[q], 60.f));
            }
    }

    #pragma unroll
    for (int i = 0; i < 2; ++i)
        #pragma unroll
        for (int q = 0; q < 4; ++q) {
            float v = lsum[i][q];
            #pragma unroll
            for (int o = 8; o; o >>= 1) v += __shfl_xor(v, o, 16);
            lsum[i][q] = v;
        }
    if (fr == 0) {
        #pragma unroll
        for (int i = 0; i < 2; ++i)
            #pragma unroll
            for (int q = 0; q < 4; ++q)
                Lp[wn][wm*32 + i*16 + (lane>>4)*4 + q] = lsum[i][q];
    }
    __syncthreads();
    if (tid < 64) invl_s[tid] = 1.f / (Lp[0][tid] + Lp[1][tid]);
    __syncthreads();

    float il[2][4];
    #pragma unroll
    for (int i = 0; i < 2; ++i)
        #pragma unroll
        for (int q = 0; q < 4; ++q)
            il[i][q] = invl_s[wm*32 + i*16 + (lane>>4)*4 + q];

    // ---------------- pass B: probs + ctx ----------------
    f32x4 cacc[2][2] = {};

    for (int kt = 0; kt < T_/64; ++kt) {
        __syncthreads();
        #pragma unroll
        for (int l = 0; l < 2; ++l) {
            int idx = tid + l * 256;
            int r = idx >> 3, c8 = (idx & 7) * 8;
            *(short8v*)&Ks[r][c8] =
                *(const short8v*)(Kb + (size_t)(b*T_ + kt*64 + r) * D_ + h*DK_ + c8);
            *(short8v*)&Vs[r][c8] =
                *(const short8v*)(VTb + (size_t)(h*DK_ + r) * M_ + b*T_ + kt*64 + c8);
        }
        __syncthreads();

        short8v aF[2][2], bF[2][2];
        #pragma unroll
        for (int i = 0; i < 2; ++i)
            #pragma unroll
            for (int k2 = 0; k2 < 2; ++k2)
                aF[i][k2] = *(const short8v*)&Qs[wm*32 + i*16 + fr][kb + k2*32];
        #pragma unroll
        for (int j = 0; j < 2; ++j)
            #pragma unroll
            for (int k2 = 0; k2 < 2; ++k2)
                bF[j][k2] = *(const short8v*)&Ks[wn*32 + j*16 + fr][kb + k2*32];

        f32x4 sacc[2][2];
        #pragma unroll
        for (int i = 0; i < 2; ++i)
            #pragma unroll
            for (int j = 0; j < 2; ++j) {
                f32x4 s = {};
                s = __builtin_amdgcn_mfma_f32_16x16x32_bf16(aF[i][0], bF[j][0], s, 0, 0, 0);
                s = __builtin_amdgcn_mfma_f32_16x16x32_bf16(aF[i][1], bF[j][1], s, 0, 0, 0);
                sacc[i][j] = s;
            }

        #pragma unroll
        for (int i = 0; i < 2; ++i)
            #pragma unroll
            for (int j = 0; j < 2; ++j) {
                #pragma unroll
                for (int q = 0; q < 4; ++q) {
                    const int qq = wm*32 + i*16 + (lane>>4)*4 + q;
                    const int kk = wn*32 + j*16 + fr;
                    float p = __expf(fminf(sacc[i][j][q], 60.f)) * il[i][q];
                    bf16 pb = f2b(p);
                    Ps[qq][kk] = *(const short*)&pb;
                    size_t go = OFFOUT + ((size_t)((b*H_+h)*T_ + q0 + qq))*T_ + kt*64 + kk;
                    if (bf) ((bf16*)dout)[go] = pb;
                    else    ((float*)dout)[go] = p;
                }
            }
        __syncthreads();

        short8v pF[2][2], vF[2][2];
        #pragma unroll
        for (int i = 0; i < 2; ++i)
            #pragma unroll
            for (int k2 = 0; k2 < 2; ++k2)
                pF[i][k2] = *(const short8v*)&Ps[wm*32 + i*16 + fr][kb + k2*32];
        #pragma unroll
        for (int j = 0; j < 2; ++j)
            #pragma unroll
            for (int k2 = 0; k2 < 2; ++k2)
                vF[j][k2] = *(const short8v*)&Vs[wn*32 + j*16 + fr][kb + k2*32];

        #pragma unroll
        for (int i = 0; i < 2; ++i)
            #pragma unroll
            for (int j = 0; j < 2; ++j) {
                cacc[i][j] = __builtin_amdgcn_mfma_f32_16x16x32_bf16(pF[i][0], vF[j][0], cacc[i][j], 0, 0, 0);
                cacc[i][j] = __builtin_amdgcn_mfma_f32_16x16x32_bf16(pF[i][1], vF[j][1], cacc[i][j], 0, 0, 0);
            }
    }

    // write ctx as bf16 hi/lo planes [m][D_]
    #pragma unroll
    for (int i = 0; i < 2; ++i)
        #pragma unroll
        for (int j = 0; j < 2; ++j)
            #pragma unroll
            for (int q = 0; q < 4; ++q) {
                const int qq = wm*32 + i*16 + (lane>>4)*4 + q;
                size_t idx = (size_t)(b*T_ + q0 + qq)*D_ + h*DK_ + wn*32 + j*16 + fr;
                float v = cacc[i][j][q];
                bf16 hh = f2b(v);
                ctxh[idx] = hh;
                ctxl[idx] = f2b(v - b2f(hh));
            }
}

// ---------------------------------------------------------------------------
// LN1: h = LayerNorm(x + attn_out) * g + b -> fp32 h AND bf16 hi/lo planes.
// ---------------------------------------------------------------------------
__global__ __launch_bounds__(256)
void ln1_kernel(const void* X, const float* __restrict__ A,
                const void* g, const void* be,
                const int* __restrict__ flag, float* __restrict__ out,
                bf16* __restrict__ hh, bf16* __restrict__ hl)
{
    const bool bf = (*flag != 0);
    const int row = blockIdx.x;
    const int tid = threadIdx.x;
    const size_t base = (size_t)row * D_;

    float v0 = ldin(X, base + tid, bf)       + A[base + tid];
    float v1 = ldin(X, base + 256 + tid, bf) + A[base + 256 + tid];
    float s  = v0 + v1;
    float sq = v0*v0 + v1*v1;
    #pragma unroll
    for (int o = 32; o; o >>= 1) { s += __shfl_xor(s, o, 64); sq += __shfl_xor(sq, o, 64); }

    __shared__ float rs[4], rq[4];
    if ((tid & 63) == 0) { rs[tid >> 6] = s; rq[tid >> 6] = sq; }
    __syncthreads();
    s  = rs[0] + rs[1] + rs[2] + rs[3];
    sq = rq[0] + rq[1] + rq[2] + rq[3];

    float mu   = s * (1.f / D_);
    float var  = sq * (1.f / D_) - mu * mu;
    float rstd = rsqrtf(var + 1e-5f);
    float y0 = (v0 - mu) * rstd * ldin(g, tid, bf)       + ldin(be, tid, bf);
    float y1 = (v1 - mu) * rstd * ldin(g, 256 + tid, bf) + ldin(be, 256 + tid, bf);
    out[base + tid]       = y0;
    out[base + 256 + tid] = y1;
    bf16 h0 = f2b(y0); hh[base + tid] = h0;       hl[base + tid]       = f2b(y0 - b2f(h0));
    bf16 h1 = f2b(y1); hh[base + 256 + tid] = h1; hl[base + 256 + tid] = f2b(y1 - b2f(h1));
}

// ---------------------------------------------------------------------------
// LN2: out = LayerNorm(h + ffn2) * g + b -> d_out (dtype per flag)
// ---------------------------------------------------------------------------
__global__ __launch_bounds__(256)
void ln2_kernel(const float* __restrict__ Hf, const float* __restrict__ F,
                const void* g, const void* be,
                const int* __restrict__ flag, void* out)
{
    const bool bf = (*flag != 0);
    const int row = blockIdx.x;
    const int tid = threadIdx.x;
    const size_t base = (size_t)row * D_;

    float v0 = Hf[base + tid]       + F[base + tid];
    float v1 = Hf[base + 256 + tid] + F[base + 256 + tid];
    float s  = v0 + v1;
    float sq = v0*v0 + v1*v1;
    #pragma unroll
    for (int o = 32; o; o >>= 1) { s += __shfl_xor(s, o, 64); sq += __shfl_xor(sq, o, 64); }

    __shared__ float rs[4], rq[4];
    if ((tid & 63) == 0) { rs[tid >> 6] = s; rq[tid >> 6] = sq; }
    __syncthreads();
    s  = rs[0] + rs[1] + rs[2] + rs[3];
    sq = rq[0] + rq[1] + rq[2] + rq[3];

    float mu   = s * (1.f / D_);
    float var  = sq * (1.f / D_) - mu * mu;
    float rstd = rsqrtf(var + 1e-5f);
    stout(out, base + tid,       (v0 - mu) * rstd * ldin(g, tid, bf)       + ldin(be, tid, bf),       bf);
    stout(out, base + 256 + tid, (v1 - mu) * rstd * ldin(g, 256 + tid, bf) + ldin(be, 256 + tid, bf), bf);
}

// ---------------------------------------------------------------------------
extern "C" void kernel_launch(void* const* d_in, const int* in_sizes, int n_in,
                              void* d_out, int out_size, void* d_ws, size_t ws_size,
                              hipStream_t stream)
{
    const void* x     = d_in[0];
    const void* wq_w  = d_in[1];
    const void* wq_b  = d_in[2];
    const void* wk_w  = d_in[3];
    const void* wk_b  = d_in[4];
    const void* wv_w  = d_in[5];
    const void* wv_b  = d_in[6];
    const void* wo_w  = d_in[7];
    const void* wo_b  = d_in[8];
    const void* ln1_g = d_in[9];
    const void* ln1_b = d_in[10];
    const void* fc1_w = d_in[11];
    const void* fc1_b = d_in[12];
    const void* fc2_w = d_in[13];
    const void* fc2_b = d_in[14];
    const void* ln2_g = d_in[15];
    const void* ln2_b = d_in[16];

    // workspace (byte offsets; total ~69 MB):
    //  [0,32M):  xh/xl/Qb/Kb/VTb/ctxh/ctxl (4 MB each; all dead before fc1)
    //            later reused as ffn1h [0,16M) + ffn1l [16M,32M)
    //  [32,40M): ao (wo out) then ffn2 (both fp32, disjoint lifetimes)
    //  [40,48M): h fp32   [48,52M): hh   [52,56M): hl
    //  [56M,..): transposed bf16 hi/lo weight planes (12.6 MB), then flag
    char* W = (char*)d_ws;
    const size_t MB = 1u << 20;
    bf16*  xh    = (bf16*)(W + 0*MB);
    bf16*  xl    = (bf16*)(W + 4*MB);
    bf16*  Qb    = (bf16*)(W + 8*MB);
    bf16*  Kb    = (bf16*)(W + 12*MB);
    bf16*  VTb   = (bf16*)(W + 16*MB);
    bf16*  ctxh  = (bf16*)(W + 20*MB);
    bf16*  ctxl  = (bf16*)(W + 24*MB);
    bf16*  ffn1h = (bf16*)(W + 0*MB);
    bf16*  ffn1l = (bf16*)(W + 16*MB);
    float* ao    = (float*)(W + 32*MB);
    float* ffn2  = (float*)(W + 32*MB);
    float* h     = (float*)(W + 40*MB);
    bf16*  hh    = (bf16*)(W + 48*MB);
    bf16*  hl    = (bf16*)(W + 52*MB);
    bf16*  tw    = (bf16*)(W + 56*MB);
    const size_t SW = (size_t)D_ * D_;               // 262144
    const size_t SF = (size_t)D_ * DFF_;             // 1048576
    bf16* wqTh = tw;                 bf16* wqTl = wqTh + SW;
    bf16* wkTh = wqTl + SW;          bf16* wkTl = wkTh + SW;
    bf16* wvTh = wkTl + SW;          bf16* wvTl = wvTh + SW;
    bf16* woTh = wvTl + SW;          bf16* woTl = woTh + SW;
    bf16* f1Th = woTl + SW;          bf16* f1Tl = f1Th + SF;
    bf16* f2Th = f1Tl + SF;          bf16* f2Tl = f2Th + SF;
    int*  flag = (int*)(f2Tl + SF);

    dim3 blk(256);

    detect_dtype<<<1, 256, 0, stream>>>((const unsigned int*)x, flag);

    // pre-transpose + bf16-split weights (wq pre-scaled by 1/8)
    transpose_w<<<dim3(D_/32,   D_/32),   blk, 0, stream>>>(wq_w,  wqTh, wqTl, flag, D_,   D_,   0.125f);
    transpose_w<<<dim3(D_/32,   D_/32),   blk, 0, stream>>>(wk_w,  wkTh, wkTl, flag, D_,   D_,   1.f);
    transpose_w<<<dim3(D_/32,   D_/32),   blk, 0, stream>>>(wv_w,  wvTh, wvTl, flag, D_,   D_,   1.f);
    transpose_w<<<dim3(D_/32,   D_/32),   blk, 0, stream>>>(wo_w,  woTh, woTl, flag, D_,   D_,   1.f);
    transpose_w<<<dim3(DFF_/32, D_/32),   blk, 0, stream>>>(fc1_w, f1Th, f1Tl, flag, D_,   DFF_, 1.f);
    transpose_w<<<dim3(D_/32,   DFF_/32), blk, 0, stream>>>(fc2_w, f2Th, f2Tl, flag, DFF_, D_,   1.f);

    // split x into bf16 hi/lo planes
    split_x<<<(M_*D_)/(256*8), blk, 0, stream>>>(x, xh, xl, flag);

    // QKV projections -> bf16 (Q pre-scaled by 1/8; V written transposed)
    gemm_mfma<64,1,0,1><<<dim3(D_/64,  M_/128), blk, 0, stream>>>(xh, xl, wqTh, wqTl, wq_b, flag, Qb,  nullptr, M_, D_, D_, 0.125f);
    gemm_mfma<64,1,0,1><<<dim3(D_/64,  M_/128), blk, 0, stream>>>(xh, xl, wkTh, wkTl, wk_b, flag, Kb,  nullptr, M_, D_, D_, 1.f);
    gemm_mfma<64,1,0,3><<<dim3(D_/64,  M_/128), blk, 0, stream>>>(xh, xl, wvTh, wvTl, wv_b, flag, VTb, nullptr, M_, D_, D_, 1.f);

    // two-pass MFMA attention: normalized probs -> d_out (+M*D), ctx hi/lo
    attn_mfma<<<dim3(T_/64, H_, B_), blk, 0, stream>>>(Qb, Kb, VTb, d_out, flag, ctxh, ctxl);

    // output projection
    gemm_mfma<64,0,0,0><<<dim3(D_/64,  M_/128), blk, 0, stream>>>(ctxh, ctxl, woTh, woTl, wo_b, flag, ao, nullptr, M_, D_, D_, 1.f);

    // residual + LN1 -> h fp32 + hi/lo planes
    ln1_kernel<<<M_, 256, 0, stream>>>(x, ao, ln1_g, ln1_b, flag, h, hh, hl);

    // FFN
    gemm_mfma<128,0,1,2><<<dim3(DFF_/128, M_/128), blk, 0, stream>>>(hh, hl, f1Th, f1Tl, fc1_b, flag, ffn1h, ffn1l, M_, DFF_, D_, 1.f);
    gemm_mfma<64,0,0,0><<<dim3(D_/64,   M_/128), blk, 0, stream>>>(ffn1h, ffn1l, f2Th, f2Tl, fc2_b, flag, ffn2, nullptr, M_, D_, DFF_, 1.f);

    // residual + LN2 -> d_out
    ln2_kernel<<<M_, 256, 0, stream>>>(h, ffn2, ln2_g, ln2_b, flag, d_out);
}

// Round 6
// 607.885 us; speedup vs baseline: 1.1287x; 1.1287x over previous
//
#include <hip/hip_runtime.h>
#include <hip/hip_bf16.h>

typedef __hip_bfloat16 bf16;
typedef __attribute__((ext_vector_type(8))) short short8v;  // 8 bf16 = 4 VGPR
typedef __attribute__((ext_vector_type(4))) float f32x4;    // MFMA C/D frag

#define B_   2
#define T_   2048
#define D_   512
#define H_   8
#define DK_  64
#define DFF_ 2048
#define M_   (B_*T_)   // 4096 rows

static __device__ __forceinline__ float b2f(bf16 v) { return __bfloat162float(v); }
static __device__ __forceinline__ bf16  f2b(float v){ return __float2bfloat16(v); }

static __device__ __forceinline__ float ldin(const void* p, size_t i, bool bf) {
    return bf ? __bfloat162float(((const bf16*)p)[i]) : ((const float*)p)[i];
}
static __device__ __forceinline__ void stout(void* p, size_t i, float v, bool bf) {
    if (bf) ((bf16*)p)[i] = __float2bfloat16(v);
    else    ((float*)p)[i] = v;
}
static __device__ __forceinline__ short hi_of(float v) {
    bf16 h = f2b(v);
    return *(const short*)&h;
}
static __device__ __forceinline__ short lo_of(float v) {
    bf16 h = f2b(v);
    bf16 l = f2b(v - b2f(h));
    return *(const short*)&l;
}

// ---------------------------------------------------------------------------
// Dtype detector. flag=1 -> bf16, flag=0 -> fp32.
// ---------------------------------------------------------------------------
__global__ void detect_dtype(const unsigned int* __restrict__ x, int* __restrict__ flag)
{
    __shared__ int cnt;
    if (threadIdx.x == 0) cnt = 0;
    __syncthreads();
    int local = 0;
    for (int i = threadIdx.x; i < 1024; i += 256) {
        unsigned int lo = x[i] & 0xFFFFu;
        float v = __uint_as_float(lo << 16);
        float a = fabsf(v);
        if (a > 1e-3f && a < 16.f) local++;
    }
    atomicAdd(&cnt, local);
    __syncthreads();
    if (threadIdx.x == 0) *flag = (cnt > 512) ? 1 : 0;
}

// ---------------------------------------------------------------------------
// split_x: x [M_*D_] -> xh, xl bf16 planes (xl unused downstream in bf16 mode)
// ---------------------------------------------------------------------------
__global__ __launch_bounds__(256)
void split_x(const void* __restrict__ X, bf16* __restrict__ xh,
             bf16* __restrict__ xl, const int* __restrict__ flag)
{
    const bool bf = (*flag != 0);
    const size_t i = ((size_t)blockIdx.x * 256 + threadIdx.x) * 8;
    if (bf) {
        *(short8v*)(xh + i) = *(const short8v*)((const bf16*)X + i);
    } else {
        const float* Xf = (const float*)X + i;
        const float4 f0 = *(const float4*)(Xf);
        const float4 f1 = *(const float4*)(Xf + 4);
        const float vals[8] = {f0.x, f0.y, f0.z, f0.w, f1.x, f1.y, f1.z, f1.w};
        short8v hi, lo;
        #pragma unroll
        for (int j = 0; j < 8; ++j) {
            short th = hi_of(vals[j]);
            short tl = lo_of(vals[j]);
            hi[j] = th;
            lo[j] = tl;
        }
        *(short8v*)(xh + i) = hi;
        *(short8v*)(xl + i) = lo;
    }
}

// ---------------------------------------------------------------------------
// prep_weights: ALL six W[K][N] -> Wt_hi/lo[N][K] transposes in one launch.
// Tile-block dispatch table: 4x256 tiles (512x512 mats) + 2x1024 (FFN mats).
// qkv planes are laid out as a single [1536][512] matrix (q rows 0-511,
// k 512-1023, v 1024-1535); wq is pre-scaled by 1/8.
// ---------------------------------------------------------------------------
__global__ __launch_bounds__(256)
void prep_weights(const void* __restrict__ wq, const void* __restrict__ wk,
                  const void* __restrict__ wv, const void* __restrict__ wo,
                  const void* __restrict__ f1, const void* __restrict__ f2,
                  bf16* __restrict__ qkvTh, bf16* __restrict__ qkvTl,
                  bf16* __restrict__ woTh,  bf16* __restrict__ woTl,
                  bf16* __restrict__ f1Th,  bf16* __restrict__ f1Tl,
                  bf16* __restrict__ f2Th,  bf16* __restrict__ f2Tl,
                  const int* __restrict__ flag)
{
    const bool bf = (*flag != 0);
    int bid = blockIdx.x;
    const void* W; bf16 *oh, *ol; int K, N; float scale = 1.f;
    if (bid < 256)       { W = wq; oh = qkvTh;          ol = qkvTl;          K = 512;  N = 512;  scale = 0.125f; }
    else if (bid < 512)  { W = wk; oh = qkvTh + 262144; ol = qkvTl + 262144; K = 512;  N = 512;  bid -= 256; }
    else if (bid < 768)  { W = wv; oh = qkvTh + 524288; ol = qkvTl + 524288; K = 512;  N = 512;  bid -= 512; }
    else if (bid < 1024) { W = wo; oh = woTh;           ol = woTl;           K = 512;  N = 512;  bid -= 768; }
    else if (bid < 2048) { W = f1; oh = f1Th;           ol = f1Tl;           K = 512;  N = 2048; bid -= 1024; }
    else                 { W = f2; oh = f2Th;           ol = f2Tl;           K = 2048; N = 512;  bid -= 2048; }

    const int ntn = N / 32;
    const int n0 = (bid % ntn) * 32;
    const int k0 = (bid / ntn) * 32;

    __shared__ float tile[32][33];
    const int c  = threadIdx.x & 31;
    const int r8 = threadIdx.x >> 5;

    #pragma unroll
    for (int i = 0; i < 4; ++i) {
        int r = r8 + i * 8;
        tile[r][c] = ldin(W, (size_t)(k0 + r) * N + n0 + c, bf) * scale;
    }
    __syncthreads();
    #pragma unroll
    for (int i = 0; i < 4; ++i) {
        int r = r8 + i * 8;                  // n within tile
        float v = tile[c][r];                // = scale * W[k0+c][n0+r]
        bf16 h = f2b(v);
        oh[(size_t)(n0 + r) * K + k0 + c] = h;
        if (!bf) ol[(size_t)(n0 + r) * K + k0 + c] = f2b(v - b2f(h));
    }
}

// ---------------------------------------------------------------------------
// Fused QKV GEMM: A = x hi/lo planes [M][512]; B = qkv planes [1536][512].
// Epilogue routes by column region: [0,512) -> Qb (bias*0.125), [512,1024)
// -> Kb, [1024,1536) -> VTb transposed. 64x64 tile, BK=32, 4 waves (2x2).
// In bf16 mode A is exact (xh only) and weights exact -> 1 MFMA/frag;
// fp32 mode: Ah*Bh + Al*Bh + Ah*Bl.
// ---------------------------------------------------------------------------
__global__ __launch_bounds__(256)
void gemm_qkv(const bf16* __restrict__ Ahg, const bf16* __restrict__ Alg,
              const bf16* __restrict__ BTh, const bf16* __restrict__ BTl,
              const void* __restrict__ qbias, const void* __restrict__ kbias,
              const void* __restrict__ vbias, const int* __restrict__ flag,
              bf16* __restrict__ Qb, bf16* __restrict__ Kb, bf16* __restrict__ VTb)
{
    const int  K     = D_;
    const bool bfw   = (*flag != 0);
    const bool useAl = !bfw;      // x exact in bf16 mode
    const bool useBl = !bfw;

    __shared__ short As[2][64][40];
    __shared__ short Bs[2][64][40];

    const int tid  = threadIdx.x;
    const int lane = tid & 63;
    const int wave = tid >> 6;
    const int wm   = wave >> 1;
    const int wn   = wave & 1;
    const int rowBase = blockIdx.y * 64;
    const int colBase = blockIdx.x * 64;

    const int fr = lane & 15;
    const int kb = (lane >> 4) * 8;
    const int srow = tid >> 2;
    const int skc  = (tid & 3) * 8;

    const bf16* aHs = Ahg + (size_t)(rowBase + srow) * K + skc;
    const bf16* aLs = Alg + (size_t)(rowBase + srow) * K + skc;
    const bf16* bHs = BTh + (size_t)(colBase + srow) * K + skc;
    const bf16* bLs = BTl + (size_t)(colBase + srow) * K + skc;

    f32x4 acc[2][2] = {};

    for (int k0 = 0; k0 < K; k0 += 32) {
        __syncthreads();
        *(short8v*)&As[0][srow][skc] = *(const short8v*)(aHs + k0);
        if (useAl) *(short8v*)&As[1][srow][skc] = *(const short8v*)(aLs + k0);
        *(short8v*)&Bs[0][srow][skc] = *(const short8v*)(bHs + k0);
        if (useBl) *(short8v*)&Bs[1][srow][skc] = *(const short8v*)(bLs + k0);
        __syncthreads();

        short8v aH[2], aL[2], bH[2], bL[2];
        #pragma unroll
        for (int f = 0; f < 2; ++f) {
            aH[f] = *(const short8v*)&As[0][wm * 32 + f * 16 + fr][kb];
            bH[f] = *(const short8v*)&Bs[0][wn * 32 + f * 16 + fr][kb];
        }
        if (useAl) {
            #pragma unroll
            for (int f = 0; f < 2; ++f)
                aL[f] = *(const short8v*)&As[1][wm * 32 + f * 16 + fr][kb];
        }
        if (useBl) {
            #pragma unroll
            for (int f = 0; f < 2; ++f)
                bL[f] = *(const short8v*)&Bs[1][wn * 32 + f * 16 + fr][kb];
        }

        #pragma unroll
        for (int i = 0; i < 2; ++i)
            #pragma unroll
            for (int j = 0; j < 2; ++j) {
                acc[i][j] = __builtin_amdgcn_mfma_f32_16x16x32_bf16(aH[i], bH[j], acc[i][j], 0, 0, 0);
                if (useAl)
                    acc[i][j] = __builtin_amdgcn_mfma_f32_16x16x32_bf16(aL[i], bH[j], acc[i][j], 0, 0, 0);
                if (useBl)
                    acc[i][j] = __builtin_amdgcn_mfma_f32_16x16x32_bf16(aH[i], bL[j], acc[i][j], 0, 0, 0);
            }
    }

    // epilogue with region routing (colBase is 64-aligned -> single region)
    const int region = colBase >> 9;
    const void* bp = (region == 0) ? qbias : (region == 1) ? kbias : vbias;
    const float bs = (region == 0) ? 0.125f : 1.f;
    const int rq = (lane >> 4) * 4;
    #pragma unroll
    for (int j = 0; j < 2; ++j) {
        const int col = colBase + wn * 32 + j * 16 + fr;
        const int lc  = col - (region << 9);
        const float bv = ldin(bp, lc, bfw) * bs;
        #pragma unroll
        for (int i = 0; i < 2; ++i) {
            #pragma unroll
            for (int q = 0; q < 4; ++q) {
                float v = acc[i][j][q] + bv;
                const int row = rowBase + wm * 32 + i * 16 + rq + q;
                if (region == 0)      Qb[(size_t)row * D_ + lc] = f2b(v);
                else if (region == 1) Kb[(size_t)row * D_ + lc] = f2b(v);
                else                  VTb[(size_t)lc * M_ + row] = f2b(v);
            }
        }
    }
}

// ---------------------------------------------------------------------------
// General MFMA GEMM, pre-split operands (A always split intermediate).
// C[M,N] = A @ B + bias, optional ReLU. OBF: 0 fp32 out, 2 bf16 hi/lo out.
// 64x64 tile, BK=32, 4 waves (2x2). Products: AhBh + AlBh (+ AhBl if fp32 W).
// ---------------------------------------------------------------------------
template<int RELU, int OBF>
__global__ __launch_bounds__(256)
void gemm_mfma(const bf16* __restrict__ Ahg, const bf16* __restrict__ Alg,
               const bf16* __restrict__ BTh, const bf16* __restrict__ BTl,
               const void* __restrict__ bias, const int* __restrict__ flag,
               void* __restrict__ C, bf16* __restrict__ Cl,
               int M, int N, int K)
{
    const bool bfw   = (*flag != 0);
    const bool useBl = !bfw;

    __shared__ short As[2][64][40];
    __shared__ short Bs[2][64][40];

    const int tid  = threadIdx.x;
    const int lane = tid & 63;
    const int wave = tid >> 6;
    const int wm   = wave >> 1;
    const int wn   = wave & 1;
    const int rowBase = blockIdx.y * 64;
    const int colBase = blockIdx.x * 64;

    const int fr = lane & 15;
    const int kb = (lane >> 4) * 8;
    const int srow = tid >> 2;
    const int skc  = (tid & 3) * 8;

    const bf16* aHs = Ahg + (size_t)(rowBase + srow) * K + skc;
    const bf16* aLs = Alg + (size_t)(rowBase + srow) * K + skc;
    const bf16* bHs = BTh + (size_t)(colBase + srow) * K + skc;
    const bf16* bLs = BTl + (size_t)(colBase + srow) * K + skc;

    f32x4 acc[2][2] = {};

    for (int k0 = 0; k0 < K; k0 += 32) {
        __syncthreads();
        *(short8v*)&As[0][srow][skc] = *(const short8v*)(aHs + k0);
        *(short8v*)&As[1][srow][skc] = *(const short8v*)(aLs + k0);
        *(short8v*)&Bs[0][srow][skc] = *(const short8v*)(bHs + k0);
        if (useBl) *(short8v*)&Bs[1][srow][skc] = *(const short8v*)(bLs + k0);
        __syncthreads();

        short8v aH[2], aL[2], bH[2], bL[2];
        #pragma unroll
        for (int f = 0; f < 2; ++f) {
            aH[f] = *(const short8v*)&As[0][wm * 32 + f * 16 + fr][kb];
            aL[f] = *(const short8v*)&As[1][wm * 32 + f * 16 + fr][kb];
            bH[f] = *(const short8v*)&Bs[0][wn * 32 + f * 16 + fr][kb];
        }
        if (useBl) {
            #pragma unroll
            for (int f = 0; f < 2; ++f)
                bL[f] = *(const short8v*)&Bs[1][wn * 32 + f * 16 + fr][kb];
        }

        #pragma unroll
        for (int i = 0; i < 2; ++i)
            #pragma unroll
            for (int j = 0; j < 2; ++j) {
                acc[i][j] = __builtin_amdgcn_mfma_f32_16x16x32_bf16(aH[i], bH[j], acc[i][j], 0, 0, 0);
                acc[i][j] = __builtin_amdgcn_mfma_f32_16x16x32_bf16(aL[i], bH[j], acc[i][j], 0, 0, 0);
                if (useBl)
                    acc[i][j] = __builtin_amdgcn_mfma_f32_16x16x32_bf16(aH[i], bL[j], acc[i][j], 0, 0, 0);
            }
    }

    const int rq = (lane >> 4) * 4;
    #pragma unroll
    for (int j = 0; j < 2; ++j) {
        const int col = colBase + wn * 32 + j * 16 + fr;
        const float bv = ldin(bias, col, bfw);
        #pragma unroll
        for (int i = 0; i < 2; ++i) {
            #pragma unroll
            for (int q = 0; q < 4; ++q) {
                float v = acc[i][j][q] + bv;
                if (RELU) v = fmaxf(v, 0.f);
                const int row = rowBase + wm * 32 + i * 16 + rq + q;
                const size_t idx = (size_t)row * N + col;
                if (OBF == 0) {
                    ((float*)C)[idx] = v;
                } else {
                    bf16 h = f2b(v);
                    ((bf16*)C)[idx] = h;
                    Cl[idx] = f2b(v - b2f(h));
                }
            }
        }
    }
}

// ---------------------------------------------------------------------------
// Two-pass MFMA attention (verified; unchanged core). Emits normalized probs
// to d_out (+M*D) and ctx as bf16 hi/lo planes.
// ---------------------------------------------------------------------------
__global__ __launch_bounds__(256)
void attn_mfma(const bf16* __restrict__ Qb, const bf16* __restrict__ Kb,
               const bf16* __restrict__ VTb, void* __restrict__ dout,
               const int* __restrict__ flag,
               bf16* __restrict__ ctxh, bf16* __restrict__ ctxl)
{
    const bool bf = (*flag != 0);
    const int tid  = threadIdx.x;
    const int lane = tid & 63;
    const int wave = tid >> 6;
    const int wm = wave >> 1, wn = wave & 1;
    const int q0 = blockIdx.x * 64;
    const int h  = blockIdx.y;
    const int b  = blockIdx.z;
    const size_t OFFOUT = (size_t)M_ * D_;

    __shared__ short Qs[64][72];
    __shared__ short Ks[64][72];
    __shared__ short Vs[64][72];
    __shared__ short Ps[64][72];
    __shared__ float Lp[2][64];
    __shared__ float invl_s[64];

    const int fr = lane & 15;
    const int kb = (lane >> 4) * 8;

    #pragma unroll
    for (int l = 0; l < 2; ++l) {
        int idx = tid + l * 256;
        int r = idx >> 3, c8 = (idx & 7) * 8;
        *(short8v*)&Qs[r][c8] =
            *(const short8v*)(Qb + (size_t)(b*T_ + q0 + r) * D_ + h*DK_ + c8);
    }

    // ---------------- pass A: denominators ----------------
    float lsum[2][4] = {};

    for (int kt = 0; kt < T_/64; ++kt) {
        __syncthreads();
        #pragma unroll
        for (int l = 0; l < 2; ++l) {
            int idx = tid + l * 256;
            int r = idx >> 3, c8 = (idx & 7) * 8;
            *(short8v*)&Ks[r][c8] =
                *(const short8v*)(Kb + (size_t)(b*T_ + kt*64 + r) * D_ + h*DK_ + c8);
        }
        __syncthreads();

        short8v aF[2][2], bF[2][2];
        #pragma unroll
        for (int i = 0; i < 2; ++i)
            #pragma unroll
            for (int k2 = 0; k2 < 2; ++k2)
                aF[i][k2] = *(const short8v*)&Qs[wm*32 + i*16 + fr][kb + k2*32];
        #pragma unroll
        for (int j = 0; j < 2; ++j)
            #pragma unroll
            for (int k2 = 0; k2 < 2; ++k2)
                bF[j][k2] = *(const short8v*)&Ks[wn*32 + j*16 + fr][kb + k2*32];

        #pragma unroll
        for (int i = 0; i < 2; ++i)
            #pragma unroll
            for (int j = 0; j < 2; ++j) {
                f32x4 s = {};
                s = __builtin_amdgcn_mfma_f32_16x16x32_bf16(aF[i][0], bF[j][0], s, 0, 0, 0);
                s = __builtin_amdgcn_mfma_f32_16x16x32_bf16(aF[i][1], bF[j][1], s, 0, 0, 0);
                #pragma unroll
                for (int q = 0; q < 4; ++q)
                    lsum[i][q] += __expf(fminf(s[q], 60.f));
            }
    }

    #pragma unroll
    for (int i = 0; i < 2; ++i)
        #pragma unroll
        for (int q = 0; q < 4; ++q) {
            float v = lsum[i][q];
            #pragma unroll
            for (int o = 8; o; o >>= 1) v += __shfl_xor(v, o, 16);
            lsum[i][q] = v;
        }
    if (fr == 0) {
        #pragma unroll
        for (int i = 0; i < 2; ++i)
            #pragma unroll
            for (int q = 0; q < 4; ++q)
                Lp[wn][wm*32 + i*16 + (lane>>4)*4 + q] = lsum[i][q];
    }
    __syncthreads();
    if (tid < 64) invl_s[tid] = 1.f / (Lp[0][tid] + Lp[1][tid]);
    __syncthreads();

    float il[2][4];
    #pragma unroll
    for (int i = 0; i < 2; ++i)
        #pragma unroll
        for (int q = 0; q < 4; ++q)
            il[i][q] = invl_s[wm*32 + i*16 + (lane>>4)*4 + q];

    // ---------------- pass B: probs + ctx ----------------
    f32x4 cacc[2][2] = {};

    for (int kt = 0; kt < T_/64; ++kt) {
        __syncthreads();
        #pragma unroll
        for (int l = 0; l < 2; ++l) {
            int idx = tid + l * 256;
            int r = idx >> 3, c8 = (idx & 7) * 8;
            *(short8v*)&Ks[r][c8] =
                *(const short8v*)(Kb + (size_t)(b*T_ + kt*64 + r) * D_ + h*DK_ + c8);
            *(short8v*)&Vs[r][c8] =
                *(const short8v*)(VTb + (size_t)(h*DK_ + r) * M_ + b*T_ + kt*64 + c8);
        }
        __syncthreads();

        short8v aF[2][2], bF[2][2];
        #pragma unroll
        for (int i = 0; i < 2; ++i)
            #pragma unroll
            for (int k2 = 0; k2 < 2; ++k2)
                aF[i][k2] = *(const short8v*)&Qs[wm*32 + i*16 + fr][kb + k2*32];
        #pragma unroll
        for (int j = 0; j < 2; ++j)
            #pragma unroll
            for (int k2 = 0; k2 < 2; ++k2)
                bF[j][k2] = *(const short8v*)&Ks[wn*32 + j*16 + fr][kb + k2*32];

        f32x4 sacc[2][2];
        #pragma unroll
        for (int i = 0; i < 2; ++i)
            #pragma unroll
            for (int j = 0; j < 2; ++j) {
                f32x4 s = {};
                s = __builtin_amdgcn_mfma_f32_16x16x32_bf16(aF[i][0], bF[j][0], s, 0, 0, 0);
                s = __builtin_amdgcn_mfma_f32_16x16x32_bf16(aF[i][1], bF[j][1], s, 0, 0, 0);
                sacc[i][j] = s;
            }

        #pragma unroll
        for (int i = 0; i < 2; ++i)
            #pragma unroll
            for (int j = 0; j < 2; ++j) {
                #pragma unroll
                for (int q = 0; q < 4; ++q) {
                    const int qq = wm*32 + i*16 + (lane>>4)*4 + q;
                    const int kk = wn*32 + j*16 + fr;
                    float p = __expf(fminf(sacc[i][j][q], 60.f)) * il[i][q];
                    bf16 pb = f2b(p);
                    Ps[qq][kk] = *(const short*)&pb;
                    size_t go = OFFOUT + ((size_t)((b*H_+h)*T_ + q0 + qq))*T_ + kt*64 + kk;
                    if (bf) ((bf16*)dout)[go] = pb;
                    else    ((float*)dout)[go] = p;
                }
            }
        __syncthreads();

        short8v pF[2][2], vF[2][2];
        #pragma unroll
        for (int i = 0; i < 2; ++i)
            #pragma unroll
            for (int k2 = 0; k2 < 2; ++k2)
                pF[i][k2] = *(const short8v*)&Ps[wm*32 + i*16 + fr][kb + k2*32];
        #pragma unroll
        for (int j = 0; j < 2; ++j)
            #pragma unroll
            for (int k2 = 0; k2 < 2; ++k2)
                vF[j][k2] = *(const short8v*)&Vs[wn*32 + j*16 + fr][kb + k2*32];

        #pragma unroll
        for (int i = 0; i < 2; ++i)
            #pragma unroll
            for (int j = 0; j < 2; ++j) {
                cacc[i][j] = __builtin_amdgcn_mfma_f32_16x16x32_bf16(pF[i][0], vF[j][0], cacc[i][j], 0, 0, 0);
                cacc[i][j] = __builtin_amdgcn_mfma_f32_16x16x32_bf16(pF[i][1], vF[j][1], cacc[i][j], 0, 0, 0);
            }
    }

    #pragma unroll
    for (int i = 0; i < 2; ++i)
        #pragma unroll
        for (int j = 0; j < 2; ++j)
            #pragma unroll
            for (int q = 0; q < 4; ++q) {
                const int qq = wm*32 + i*16 + (lane>>4)*4 + q;
                size_t idx = (size_t)(b*T_ + q0 + qq)*D_ + h*DK_ + wn*32 + j*16 + fr;
                float v = cacc[i][j][q];
                bf16 hh = f2b(v);
                ctxh[idx] = hh;
                ctxl[idx] = f2b(v - b2f(hh));
            }
}

// ---------------------------------------------------------------------------
// LN1: h = LayerNorm(x + attn_out) * g + b -> bf16 hi/lo planes only.
// ---------------------------------------------------------------------------
__global__ __launch_bounds__(256)
void ln1_kernel(const void* X, const float* __restrict__ A,
                const void* g, const void* be,
                const int* __restrict__ flag,
                bf16* __restrict__ hh, bf16* __restrict__ hl)
{
    const bool bf = (*flag != 0);
    const int row = blockIdx.x;
    const int tid = threadIdx.x;
    const size_t base = (size_t)row * D_;

    float v0 = ldin(X, base + tid, bf)       + A[base + tid];
    float v1 = ldin(X, base + 256 + tid, bf) + A[base + 256 + tid];
    float s  = v0 + v1;
    float sq = v0*v0 + v1*v1;
    #pragma unroll
    for (int o = 32; o; o >>= 1) { s += __shfl_xor(s, o, 64); sq += __shfl_xor(sq, o, 64); }

    __shared__ float rs[4], rq[4];
    if ((tid & 63) == 0) { rs[tid >> 6] = s; rq[tid >> 6] = sq; }
    __syncthreads();
    s  = rs[0] + rs[1] + rs[2] + rs[3];
    sq = rq[0] + rq[1] + rq[2] + rq[3];

    float mu   = s * (1.f / D_);
    float var  = sq * (1.f / D_) - mu * mu;
    float rstd = rsqrtf(var + 1e-5f);
    float y0 = (v0 - mu) * rstd * ldin(g, tid, bf)       + ldin(be, tid, bf);
    float y1 = (v1 - mu) * rstd * ldin(g, 256 + tid, bf) + ldin(be, 256 + tid, bf);
    bf16 h0 = f2b(y0); hh[base + tid] = h0;       hl[base + tid]       = f2b(y0 - b2f(h0));
    bf16 h1 = f2b(y1); hh[base + 256 + tid] = h1; hl[base + 256 + tid] = f2b(y1 - b2f(h1));
}

// ---------------------------------------------------------------------------
// LN2: out = LayerNorm((hh+hl) + ffn2) * g + b -> d_out (dtype per flag)
// ---------------------------------------------------------------------------
__global__ __launch_bounds__(256)
void ln2_kernel(const bf16* __restrict__ hh, const bf16* __restrict__ hl,
                const float* __restrict__ F,
                const void* g, const void* be,
                const int* __restrict__ flag, void* out)
{
    const bool bf = (*flag != 0);
    const int row = blockIdx.x;
    const int tid = threadIdx.x;
    const size_t base = (size_t)row * D_;

    float v0 = b2f(hh[base + tid])       + b2f(hl[base + tid])       + F[base + tid];
    float v1 = b2f(hh[base + 256 + tid]) + b2f(hl[base + 256 + tid]) + F[base + 256 + tid];
    float s  = v0 + v1;
    float sq = v0*v0 + v1*v1;
    #pragma unroll
    for (int o = 32; o; o >>= 1) { s += __shfl_xor(s, o, 64); sq += __shfl_xor(sq, o, 64); }

    __shared__ float rs[4], rq[4];
    if ((tid & 63) == 0) { rs[tid >> 6] = s; rq[tid >> 6] = sq; }
    __syncthreads();
    s  = rs[0] + rs[1] + rs[2] + rs[3];
    sq = rq[0] + rq[1] + rq[2] + rq[3];

    float mu   = s * (1.f / D_);
    float var  = sq * (1.f / D_) - mu * mu;
    float rstd = rsqrtf(var + 1e-5f);
    stout(out, base + tid,       (v0 - mu) * rstd * ldin(g, tid, bf)       + ldin(be, tid, bf),       bf);
    stout(out, base + 256 + tid, (v1 - mu) * rstd * ldin(g, 256 + tid, bf) + ldin(be, 256 + tid, bf), bf);
}

// ---------------------------------------------------------------------------
extern "C" void kernel_launch(void* const* d_in, const int* in_sizes, int n_in,
                              void* d_out, int out_size, void* d_ws, size_t ws_size,
                              hipStream_t stream)
{
    const void* x     = d_in[0];
    const void* wq_w  = d_in[1];
    const void* wq_b  = d_in[2];
    const void* wk_w  = d_in[3];
    const void* wk_b  = d_in[4];
    const void* wv_w  = d_in[5];
    const void* wv_b  = d_in[6];
    const void* wo_w  = d_in[7];
    const void* wo_b  = d_in[8];
    const void* ln1_g = d_in[9];
    const void* ln1_b = d_in[10];
    const void* fc1_w = d_in[11];
    const void* fc1_b = d_in[12];
    const void* fc2_w = d_in[13];
    const void* fc2_b = d_in[14];
    const void* ln2_g = d_in[15];
    const void* ln2_b = d_in[16];

    // workspace (byte offsets; ~60 MB):
    //  [0,4M) xh  [4,8M) xl  [8,12M) Qb  [12,16M) Kb  [16,20M) VTb
    //  [20,24M) ctxh  [24,28M) ctxl
    //  ffn1h aliases [0,16M), ffn1l aliases [16,32M) (producers all dead)
    //  [32,40M) ao fp32 (wo out), then ffn2 fp32 (disjoint lifetimes)
    //  [40,44M) hh  [44,48M) hl
    //  [48M,..) weight planes (12 MB), then flag
    char* W = (char*)d_ws;
    const size_t MB = 1u << 20;
    bf16*  xh    = (bf16*)(W + 0*MB);
    bf16*  xl    = (bf16*)(W + 4*MB);
    bf16*  Qb    = (bf16*)(W + 8*MB);
    bf16*  Kb    = (bf16*)(W + 12*MB);
    bf16*  VTb   = (bf16*)(W + 16*MB);
    bf16*  ctxh  = (bf16*)(W + 20*MB);
    bf16*  ctxl  = (bf16*)(W + 24*MB);
    bf16*  ffn1h = (bf16*)(W + 0*MB);
    bf16*  ffn1l = (bf16*)(W + 16*MB);
    float* ao    = (float*)(W + 32*MB);
    float* ffn2  = (float*)(W + 32*MB);
    bf16*  hh    = (bf16*)(W + 40*MB);
    bf16*  hl    = (bf16*)(W + 44*MB);
    bf16*  tw    = (bf16*)(W + 48*MB);
    const size_t SQKV = (size_t)1536 * 512;          // 786432
    const size_t SW   = (size_t)D_ * D_;             // 262144
    const size_t SF   = (size_t)D_ * DFF_;           // 1048576
    bf16* qkvTh = tw;               bf16* qkvTl = qkvTh + SQKV;
    bf16* woTh  = qkvTl + SQKV;     bf16* woTl  = woTh + SW;
    bf16* f1Th  = woTl + SW;        bf16* f1Tl  = f1Th + SF;
    bf16* f2Th  = f1Tl + SF;        bf16* f2Tl  = f2Th + SF;
    int*  flag  = (int*)(f2Tl + SF);

    dim3 blk(256);

    detect_dtype<<<1, 256, 0, stream>>>((const unsigned int*)x, flag);

    // all weight transposes + bf16 splits in one launch (wq pre-scaled 1/8)
    prep_weights<<<3072, blk, 0, stream>>>(wq_w, wk_w, wv_w, wo_w, fc1_w, fc2_w,
                                           qkvTh, qkvTl, woTh, woTl,
                                           f1Th, f1Tl, f2Th, f2Tl, flag);

    // split x into bf16 hi/lo planes
    split_x<<<(M_*D_)/(256*8), blk, 0, stream>>>(x, xh, xl, flag);

    // fused QKV projection (Q scaled 1/8; V written transposed)
    gemm_qkv<<<dim3(1536/64, M_/64), blk, 0, stream>>>(xh, xl, qkvTh, qkvTl,
                                                       wq_b, wk_b, wv_b, flag,
                                                       Qb, Kb, VTb);

    // two-pass MFMA attention: normalized probs -> d_out (+M*D), ctx hi/lo
    attn_mfma<<<dim3(T_/64, H_, B_), blk, 0, stream>>>(Qb, Kb, VTb, d_out, flag, ctxh, ctxl);

    // output projection -> ao fp32
    gemm_mfma<0,0><<<dim3(D_/64, M_/64), blk, 0, stream>>>(ctxh, ctxl, woTh, woTl,
                                                           wo_b, flag, ao, nullptr,
                                                           M_, D_, D_);

    // residual + LN1 -> h hi/lo planes
    ln1_kernel<<<M_, 256, 0, stream>>>(x, ao, ln1_g, ln1_b, flag, hh, hl);

    // FFN
    gemm_mfma<1,2><<<dim3(DFF_/64, M_/64), blk, 0, stream>>>(hh, hl, f1Th, f1Tl,
                                                             fc1_b, flag, ffn1h, ffn1l,
                                                             M_, DFF_, D_);
    gemm_mfma<0,0><<<dim3(D_/64, M_/64), blk, 0, stream>>>(ffn1h, ffn1l, f2Th, f2Tl,
                                                           fc2_b, flag, ffn2, nullptr,
                                                           M_, D_, DFF_);

    // residual + LN2 -> d_out
    ln2_kernel<<<M_, 256, 0, stream>>>(hh, hl, ffn2, ln2_g, ln2_b, flag, d_out);
}